// Round 8
// baseline (591.405 us; speedup 1.0000x reference)
//
#include <hip/hip_runtime.h>

#define NSEQ 512
#define DCH 128
#define RTOT (NSEQ * NSEQ) /* 262144 */

typedef __attribute__((ext_vector_type(8))) short bf16x8;
typedef __attribute__((ext_vector_type(4))) float f32x4;

__device__ __forceinline__ unsigned short f2bf(float v) {
  union { float f; unsigned int u; } x; x.f = v;
  unsigned int u = x.u;
  return (unsigned short)((u + 0x7fffu + ((u >> 16) & 1u)) >> 16);
}
__device__ __forceinline__ float bf2f(unsigned short s) {
  union { unsigned int u; float f; } x; x.u = ((unsigned int)s) << 16;
  return x.f;
}
__device__ __forceinline__ float sigmoidf(float x) { return 1.f / (1.f + __expf(-x)); }

// async global->LDS, 16B per lane; LDS dst is wave-uniform base (+ lane*16 implicit)
__device__ __forceinline__ void async16(const unsigned short* g, unsigned short* l) {
  __builtin_amdgcn_global_load_lds(
      (const __attribute__((address_space(1))) unsigned int*)g,
      (__attribute__((address_space(3))) unsigned int*)l, 16, 0, 0);
}

// ---------------------------------------------------------------------------
// prep: pack weights (reordered) into bf16.  Wc rows: [0,128)=to-feat,
// [128,256)=to-gate, [256,384)=from-feat, [384,512)=from-gate, [512,640)=go.
// ---------------------------------------------------------------------------
__global__ void prep_kernel(const float* __restrict__ W_fg, const float* __restrict__ b_fg,
                            const float* __restrict__ W_go, const float* __restrict__ b_go,
                            const float* __restrict__ W_out,
                            unsigned short* __restrict__ Wc, float* __restrict__ bc,
                            unsigned short* __restrict__ Woutb) {
  int idx = blockIdx.x * 256 + threadIdx.x;
  if (idx < 640 * 128) {
    int rr = idx >> 7, k = idx & 127;
    float v, bv;
    if (rr < 512) {
      int m = rr >> 7;
      int srow = (m == 1) ? rr + 128 : (m == 2) ? rr - 128 : rr;
      v = W_fg[srow * 128 + k];
      bv = b_fg[srow];
    } else {
      int srow = rr - 512;
      v = W_go[srow * 128 + k];
      bv = b_go[srow];
    }
    Wc[idx] = f2bf(v);
    if (k == 0) bc[rr] = bv;
  } else {
    int i2 = idx - 640 * 128;
    if (i2 < 128 * 128) Woutb[i2] = f2bf(W_out[i2]);
  }
}

// ---------------------------------------------------------------------------
// K0: LayerNorm over last dim (128) of edges; write x as bf16. 1 wave = 1 row.
// ---------------------------------------------------------------------------
__global__ __launch_bounds__(256) void ln1_kernel(const float* __restrict__ edges,
                                                  const float* __restrict__ w,
                                                  const float* __restrict__ b,
                                                  unsigned short* __restrict__ xb) {
  int wv = threadIdx.x >> 6;
  int lane = threadIdx.x & 63;
  size_t row = (size_t)blockIdx.x * 4 + wv;
  const float2* e = (const float2*)(edges + row * 128);
  float2 v = e[lane];
  float s = v.x + v.y, sq = v.x * v.x + v.y * v.y;
#pragma unroll
  for (int off = 32; off; off >>= 1) {
    s += __shfl_xor(s, off);
    sq += __shfl_xor(sq, off);
  }
  float mu = s * (1.f / 128.f);
  float var = sq * (1.f / 128.f) - mu * mu;
  float rs = rsqrtf(var + 1e-5f);
  int c = lane * 2;
  float x0 = (v.x - mu) * rs * w[c] + b[c];
  float x1 = (v.y - mu) * rs * w[c + 1] + b[c + 1];
  unsigned int packed = (unsigned int)f2bf(x0) | ((unsigned int)f2bf(x1) << 16);
  ((unsigned int*)(xb + row * 128))[lane] = packed;
}

// ---------------------------------------------------------------------------
// K1a: fg GEMM + gating + mask.  Col-split waves; full prologue burst — all
// 16 A-fragments, 16 B-fragments, masks, biases in registers up front.
// m-loop is pure compute.  LDS transpose epilogue -> 128B-line stores.
// ---------------------------------------------------------------------------
__global__ __launch_bounds__(256) void fg_gemm_kernel(
    const unsigned short* __restrict__ xb, const unsigned short* __restrict__ Wc,
    const float* __restrict__ bc, const int* __restrict__ mask,
    unsigned short* __restrict__ toT, unsigned short* __restrict__ fromT) {
  __shared__ unsigned int Cs[128 * 36]; // 128 planes x 64 rows bf16 (pad 36 uints/plane)
  int nb = blockIdx.y;
  int wv = threadIdx.x >> 6, lane = threadIdx.x & 63;
  int qm = lane & 15, quad = lane >> 4;
  int r0 = blockIdx.x * 64;
  int nbase = nb * 256;

  // ---- prologue: every global read issued up front ----
  bf16x8 Areg[4][4]; // [m][kk] — static indexing only (full unroll)
#pragma unroll
  for (int m = 0; m < 4; m++)
#pragma unroll
    for (int kk = 0; kk < 4; kk++)
      Areg[m][kk] = *(const bf16x8*)(xb + (size_t)(r0 + m * 16 + qm) * 128 + kk * 32 + quad * 8);

  bf16x8 Bf[2][4], Bg[2][4];
#pragma unroll
  for (int ft = 0; ft < 2; ft++)
#pragma unroll
    for (int kk = 0; kk < 4; kk++) {
      int ko = kk * 32 + quad * 8;
      Bf[ft][kk] = *(const bf16x8*)(Wc + (size_t)(nbase + wv * 32 + ft * 16 + qm) * 128 + ko);
      Bg[ft][kk] = *(const bf16x8*)(Wc + (size_t)(nbase + 128 + wv * 32 + ft * 16 + qm) * 128 + ko);
    }

  int4 mi4[4];
#pragma unroll
  for (int m = 0; m < 4; m++) mi4[m] = *(const int4*)(mask + r0 + m * 16 + quad * 4);

  float bF_[2], bG_[2];
#pragma unroll
  for (int ft = 0; ft < 2; ft++) {
    int c = wv * 32 + ft * 16 + qm;
    bF_[ft] = bc[nbase + c];
    bG_[ft] = bc[nbase + 128 + c];
  }

#pragma unroll
  for (int m = 0; m < 4; m++) { // 4 row-steps of 16 rows — pure compute now
    f32x4 accf[2], accg[2];
#pragma unroll
    for (int ft = 0; ft < 2; ft++) {
      accf[ft] = (f32x4){0.f, 0.f, 0.f, 0.f};
      accg[ft] = (f32x4){0.f, 0.f, 0.f, 0.f};
    }
#pragma unroll
    for (int kk = 0; kk < 4; kk++) {
#pragma unroll
      for (int ft = 0; ft < 2; ft++) {
        accf[ft] = __builtin_amdgcn_mfma_f32_16x16x32_bf16(Areg[m][kk], Bf[ft][kk], accf[ft], 0, 0, 0);
        accg[ft] = __builtin_amdgcn_mfma_f32_16x16x32_bf16(Areg[m][kk], Bg[ft][kk], accg[ft], 0, 0, 0);
      }
    }
    int4 mi = mi4[m];
    float mk[4] = {mi.x ? 1.f : 0.f, mi.y ? 1.f : 0.f, mi.z ? 1.f : 0.f, mi.w ? 1.f : 0.f};
#pragma unroll
    for (int ft = 0; ft < 2; ft++) {
      int c = wv * 32 + ft * 16 + qm; // local col 0..127
      float v0 = (accf[ft][0] + bF_[ft]) * sigmoidf(accg[ft][0] + bG_[ft]) * mk[0];
      float v1 = (accf[ft][1] + bF_[ft]) * sigmoidf(accg[ft][1] + bG_[ft]) * mk[1];
      float v2 = (accf[ft][2] + bF_[ft]) * sigmoidf(accg[ft][2] + bG_[ft]) * mk[2];
      float v3 = (accf[ft][3] + bF_[ft]) * sigmoidf(accg[ft][3] + bG_[ft]) * mk[3];
      unsigned int u0 = (unsigned int)f2bf(v0) | ((unsigned int)f2bf(v1) << 16);
      unsigned int u1 = (unsigned int)f2bf(v2) | ((unsigned int)f2bf(v3) << 16);
      *(uint2*)(Cs + c * 36 + m * 8 + quad * 2) = (uint2){u0, u1};
    }
  }
  __syncthreads();
  { // wave writes its own 32 planes; 8 lanes/plane -> 128B contiguous lines
    unsigned short* dst = (nb == 0) ? toT : fromT;
    int pl = lane >> 3, lo = lane & 7;
#pragma unroll
    for (int i = 0; i < 4; i++) {
      int p = wv * 32 + i * 8 + pl;
      uint4 v = *(const uint4*)(Cs + p * 36 + lo * 4);
      *(uint4*)(dst + (size_t)p * RTOT + r0 + lo * 8) = v;
    }
  }
}

// ---------------------------------------------------------------------------
// K1b (FALLBACK ONLY, used when workspace too small to de-alias triT):
// out_gate = sigmoid(x @ W_go^T + b_go) * mask, fp32, into d_out.
// ---------------------------------------------------------------------------
__global__ __launch_bounds__(256) void go_gemm_kernel(
    const unsigned short* __restrict__ xb, const unsigned short* __restrict__ Wc,
    const float* __restrict__ bc, const int* __restrict__ mask,
    float* __restrict__ gate_out) {
  int wv = threadIdx.x >> 6, lane = threadIdx.x & 63;
  int qm = lane & 15, quad = lane >> 4;
  int rw = blockIdx.x * 64 + wv * 16;

  f32x4 acc[8];
#pragma unroll
  for (int t = 0; t < 8; t++) acc[t] = (f32x4){0.f, 0.f, 0.f, 0.f};

#pragma unroll
  for (int kk = 0; kk < 4; kk++) {
    int ko = kk * 32 + quad * 8;
    bf16x8 a = *(const bf16x8*)(xb + (size_t)(rw + qm) * 128 + ko);
#pragma unroll
    for (int t = 0; t < 8; t++) {
      bf16x8 bf = *(const bf16x8*)(Wc + (size_t)(512 + t * 16 + qm) * 128 + ko);
      acc[t] = __builtin_amdgcn_mfma_f32_16x16x32_bf16(a, bf, acc[t], 0, 0, 0);
    }
  }

  int rbase = rw + quad * 4;
  int4 mi = *(const int4*)(mask + rbase);
  float mk[4] = {mi.x ? 1.f : 0.f, mi.y ? 1.f : 0.f, mi.z ? 1.f : 0.f, mi.w ? 1.f : 0.f};
#pragma unroll
  for (int t = 0; t < 8; t++) {
    int c = t * 16 + qm;
    float bG = bc[512 + c];
#pragma unroll
    for (int reg = 0; reg < 4; reg++) {
      float g = sigmoidf(acc[t][reg] + bG) * mk[reg];
      gate_out[(size_t)(rbase + reg) * 128 + c] = g;
    }
  }
}

// ---------------------------------------------------------------------------
// K2: tri[d] = To_d (512x512) @ From_d^T, 128 batched NT GEMMs.
// 128x128 tile/block, BK=64, global_load_lds(16B) staging, 4 waves x (4x4)
// MFMA accs.  XCD d-clustered swizzle (bijective).
// ---------------------------------------------------------------------------
__global__ __launch_bounds__(256) void tri_gemm_kernel(
    const unsigned short* __restrict__ toT, const unsigned short* __restrict__ fromT,
    unsigned short* __restrict__ triT) {
  __shared__ unsigned short smem[128 * 136]; // K-loop: As=[0,8192) Bs=[8192,16384); epilogue: C 128x136
  unsigned short* As = smem;
  unsigned short* Bs = smem + 128 * 64;

  // bijective remap of (x,y,z) -> (i0,j0,d), d-clustered per XCD
  int n = (int)(blockIdx.x + (blockIdx.y << 2) + (blockIdx.z << 4)); // 0..2047
  int xcd = n & 7, s = n >> 3;                                        // s: 0..255
  int d = xcd * 16 + (s >> 4);
  int xy = s & 15;
  int i0 = (xy & 3) * 128, j0 = (xy >> 2) * 128;

  int tid = threadIdx.x, w = tid >> 6, lane = tid & 63;
  int qm = lane & 15, quad = lane >> 4;
  int wm = w >> 1, wn = w & 1;
  const unsigned short* A = toT + (size_t)d * RTOT;
  const unsigned short* B = fromT + (size_t)d * RTOT;
  int lr = lane >> 3, lk = (lane & 7) * 8;

  f32x4 acc[4][4];
#pragma unroll
  for (int m = 0; m < 4; m++)
#pragma unroll
    for (int n2 = 0; n2 < 4; n2++) acc[m][n2] = (f32x4){0.f, 0.f, 0.f, 0.f};

  for (int kb = 0; kb < 512; kb += 64) {
    __syncthreads(); // prev compute done reading LDS
#pragma unroll
    for (int q = 0; q < 4; q++) {
      int blk = w * 4 + q; // 16 row-blocks of 8 rows each
      async16(A + (size_t)(i0 + blk * 8 + lr) * 512 + kb + lk, As + blk * 512);
      async16(B + (size_t)(j0 + blk * 8 + lr) * 512 + kb + lk, Bs + blk * 512);
    }
    __syncthreads(); // loads drained (compiler emits vmcnt(0) before barrier)
#pragma unroll
    for (int kk = 0; kk < 2; kk++) {
      bf16x8 af[4], bfr[4];
#pragma unroll
      for (int m = 0; m < 4; m++)
        af[m] = *(const bf16x8*)(As + (wm * 64 + m * 16 + qm) * 64 + kk * 32 + quad * 8);
#pragma unroll
      for (int n2 = 0; n2 < 4; n2++)
        bfr[n2] = *(const bf16x8*)(Bs + (wn * 64 + n2 * 16 + qm) * 64 + kk * 32 + quad * 8);
#pragma unroll
      for (int m = 0; m < 4; m++)
#pragma unroll
        for (int n2 = 0; n2 < 4; n2++)
          acc[m][n2] = __builtin_amdgcn_mfma_f32_16x16x32_bf16(af[m], bfr[n2], acc[m][n2], 0, 0, 0);
    }
  }

  __syncthreads(); // done with As/Bs; reuse smem as C 128x136 (pad keeps 16B align, kills conflicts)
#pragma unroll
  for (int m = 0; m < 4; m++) {
    int rb = wm * 64 + m * 16 + quad * 4;
#pragma unroll
    for (int n2 = 0; n2 < 4; n2++) {
      int col = wn * 64 + n2 * 16 + qm;
#pragma unroll
      for (int reg = 0; reg < 4; reg++)
        smem[(rb + reg) * 136 + col] = f2bf(acc[m][n2][reg]);
    }
  }
  __syncthreads();
  { // each (row, half) copies its FULL 64-short half: 8 x uint4
    int row = tid >> 1, half = tid & 1;
    const uint4* src = (const uint4*)(smem + row * 136 + half * 64);
    uint4 v[8];
#pragma unroll
    for (int u = 0; u < 8; u++) v[u] = src[u];
    uint4* dst = (uint4*)(triT + (size_t)d * RTOT + (size_t)(i0 + row) * 512 + j0 + half * 64);
#pragma unroll
    for (int u = 0; u < 8; u++) dst[u] = v[u];
  }
}

// ---------------------------------------------------------------------------
// K3: LN2 over d=128 of tri (channel-major input), @ W_out^T + b_out, * gate.
// ROUND-5 VERSION VERBATIM (measured 149.5us): 64-row blocks, all global
// reads in one prologue burst, gate A2 software-pipelined across m.
// (128-row variant measured 181us — reverted: VGPR 128/SGPR 112/2x LDS with
// no MLP gain.)
// ---------------------------------------------------------------------------
__global__ __launch_bounds__(256) void out_kernel(
    const unsigned short* __restrict__ triT, const unsigned short* __restrict__ Woutb,
    const float* __restrict__ ln2w, const float* __restrict__ ln2b,
    const float* __restrict__ b_out, float* __restrict__ out,
    const unsigned short* __restrict__ xb, const unsigned short* __restrict__ Wc,
    const float* __restrict__ bc, const int* __restrict__ mask, int fuse) {
  __shared__ unsigned short nt[64][136];
  __shared__ float mu_s[64], rs_s[64];
  int r0 = blockIdx.x * 64;
  int tid = threadIdx.x;
  int wv = tid >> 6, lane = tid & 63;
  int qm = lane & 15, quad = lane >> 4;

  // ---- prologue: issue every global read up front (max MLP) ----
  int dch = tid >> 1, half = tid & 1;
  const uint4* src = (const uint4*)(triT + (size_t)dch * RTOT + r0 + half * 32);
  uint4 sv0 = src[0], sv1 = src[1], sv2 = src[2], sv3 = src[3];

  // B fragments for this wave's 32 output cols.
  bf16x8 Bo[2][4], Bg[2][4];
#pragma unroll
  for (int ft = 0; ft < 2; ft++)
#pragma unroll
    for (int kk = 0; kk < 4; kk++) {
      int c = wv * 32 + ft * 16 + qm;
      int ko = kk * 32 + quad * 8;
      Bo[ft][kk] = *(const bf16x8*)(Woutb + (size_t)c * 128 + ko);
      if (fuse) Bg[ft][kk] = *(const bf16x8*)(Wc + (size_t)(512 + c) * 128 + ko);
    }

  // masks for all 4 m-steps; bias scalars.
  int4 mi4[4];
  float bo_[2], bG_[2];
#pragma unroll
  for (int ft = 0; ft < 2; ft++) {
    int c = wv * 32 + ft * 16 + qm;
    bo_[ft] = b_out[c];
    bG_[ft] = fuse ? bc[512 + c] : 0.f;
  }
  if (fuse) {
#pragma unroll
    for (int m = 0; m < 4; m++) mi4[m] = *(const int4*)(mask + r0 + m * 16 + quad * 4);
  }

  // gate A2: prefetch m=0 (double-buffered across the m-loop).
  const unsigned short* xA = xb + (size_t)(r0 + qm) * 128 + quad * 8;
  bf16x8 a2cur[4], a2nxt[4];
  if (fuse) {
#pragma unroll
    for (int kk = 0; kk < 4; kk++) a2cur[kk] = *(const bf16x8*)(xA + kk * 32);
  }

  { // LDS staging writes (vmcnt waits only on the sv0..3 loads)
    uint4 v[4] = {sv0, sv1, sv2, sv3};
    const unsigned short* pv = (const unsigned short*)v;
#pragma unroll
    for (int u = 0; u < 32; u++) nt[half * 32 + u][dch] = pv[u];
  }
  __syncthreads();

  { // LN2 stats: 4 lanes per position
    int p = tid >> 2, part = tid & 3;
    float s = 0.f, sq = 0.f;
#pragma unroll
    for (int u = 0; u < 4; u++) {
      bf16x8 v = *(const bf16x8*)(&nt[p][part * 32 + u * 8]);
#pragma unroll
      for (int e = 0; e < 8; e++) {
        float f = bf2f((unsigned short)v[e]);
        s += f; sq += f * f;
      }
    }
    s += __shfl_xor(s, 1); sq += __shfl_xor(sq, 1);
    s += __shfl_xor(s, 2); sq += __shfl_xor(sq, 2);
    float mu = s * (1.f / 128.f);
    float var = sq * (1.f / 128.f) - mu * mu;
    if (part == 0) { mu_s[p] = mu; rs_s[p] = rsqrtf(var + 1e-5f); }
  }
  __syncthreads();

#pragma unroll
  for (int m = 0; m < 4; m++) { // 4 row-steps of 16 rows
    // prefetch next m's gate A2 first: latency hides under afr VALU + MFMA
    if (fuse && m < 3) {
#pragma unroll
      for (int kk = 0; kk < 4; kk++)
        a2nxt[kk] = *(const bf16x8*)(xA + (m + 1) * 2048 + kk * 32);
    }

    int rl = m * 16 + qm;
    float mu = mu_s[rl], rs = rs_s[rl];

    // Build normalized A-fragments in registers.
    bf16x8 afr[4];
#pragma unroll
    for (int kk = 0; kk < 4; kk++) {
      int ko = kk * 32 + quad * 8;
      bf16x8 raw = *(const bf16x8*)(&nt[rl][ko]);
#pragma unroll
      for (int e = 0; e < 8; e++) {
        float wf = ln2w[ko + e], bv = ln2b[ko + e];
        afr[kk][e] = (short)f2bf((bf2f((unsigned short)raw[e]) - mu) * rs * wf + bv);
      }
    }

    f32x4 accO[2], accG[2];
#pragma unroll
    for (int ft = 0; ft < 2; ft++) {
      accO[ft] = (f32x4){0.f, 0.f, 0.f, 0.f};
      accG[ft] = (f32x4){0.f, 0.f, 0.f, 0.f};
    }
#pragma unroll
    for (int kk = 0; kk < 4; kk++) {
#pragma unroll
      for (int ft = 0; ft < 2; ft++)
        accO[ft] = __builtin_amdgcn_mfma_f32_16x16x32_bf16(afr[kk], Bo[ft][kk], accO[ft], 0, 0, 0);
      if (fuse) {
#pragma unroll
        for (int ft = 0; ft < 2; ft++)
          accG[ft] = __builtin_amdgcn_mfma_f32_16x16x32_bf16(a2cur[kk], Bg[ft][kk], accG[ft], 0, 0, 0);
      }
    }

    int rbase = r0 + m * 16 + quad * 4;
    if (fuse) {
      int4 mi = mi4[m];
      float mk[4] = {mi.x ? 1.f : 0.f, mi.y ? 1.f : 0.f, mi.z ? 1.f : 0.f, mi.w ? 1.f : 0.f};
#pragma unroll
      for (int ft = 0; ft < 2; ft++) {
        int c = wv * 32 + ft * 16 + qm;
#pragma unroll
        for (int reg = 0; reg < 4; reg++) {
          float g = sigmoidf(accG[ft][reg] + bG_[ft]) * mk[reg];
          out[(size_t)(rbase + reg) * 128 + c] = (accO[ft][reg] + bo_[ft]) * g;
        }
      }
      // rotate double-buffer (register moves, static after unroll)
#pragma unroll
      for (int kk = 0; kk < 4; kk++) a2cur[kk] = a2nxt[kk];
    } else {
#pragma unroll
      for (int ft = 0; ft < 2; ft++) {
        int c = wv * 32 + ft * 16 + qm;
#pragma unroll
        for (int reg = 0; reg < 4; reg++) {
          size_t off = (size_t)(rbase + reg) * 128 + c;
          out[off] = (accO[ft][reg] + bo_[ft]) * out[off]; // out[] holds gate
        }
      }
    }
  }
}

// ---------------------------------------------------------------------------
extern "C" void kernel_launch(void* const* d_in, const int* in_sizes, int n_in,
                              void* d_out, int out_size, void* d_ws, size_t ws_size,
                              hipStream_t stream) {
  const float* edges = (const float*)d_in[0];
  const int* mask = (const int*)d_in[1];
  const float* ln1w = (const float*)d_in[2];
  const float* ln1b = (const float*)d_in[3];
  const float* W_fg = (const float*)d_in[4];
  const float* b_fg = (const float*)d_in[5];
  const float* W_go = (const float*)d_in[6];
  const float* b_go = (const float*)d_in[7];
  const float* ln2w = (const float*)d_in[8];
  const float* ln2b = (const float*)d_in[9];
  const float* W_out = (const float*)d_in[10];
  const float* b_out = (const float*)d_in[11];

  char* ws = (char*)d_ws;
  const size_t SZ = (size_t)RTOT * DCH * 2; // 64 MiB per bf16 buffer
  const size_t WSMALL = 0x40000;            // 256 KiB: Wc(160K)+bc(2.5K)+Woutb(32K), padded
  unsigned short* xb = (unsigned short*)ws;
  unsigned short* toT = (unsigned short*)(ws + SZ);
  unsigned short* fromT = (unsigned short*)(ws + 2 * SZ);
  unsigned short* Wc = (unsigned short*)(ws + 3 * SZ);
  float* bc = (float*)(ws + 3 * SZ + 640 * 128 * 2);
  unsigned short* Woutb = (unsigned short*)(ws + 3 * SZ + 640 * 128 * 2 + 640 * 4);
  float* gate = (float*)d_out;

  // If workspace allows, give triT its own buffer so xb survives -> fuse the
  // gate GEMM into out_kernel (kills 256 MiB of fp32 gate traffic + 1 launch).
  bool fits = ws_size >= 4 * SZ + WSMALL;
  unsigned short* triT = fits ? (unsigned short*)(ws + 3 * SZ + WSMALL) : xb;

  prep_kernel<<<384, 256, 0, stream>>>(W_fg, b_fg, W_go, b_go, W_out, Wc, bc, Woutb);
  ln1_kernel<<<RTOT / 4, 256, 0, stream>>>(edges, ln1w, ln1b, xb);
  fg_gemm_kernel<<<dim3(RTOT / 64, 2), 256, 0, stream>>>(xb, Wc, bc, mask, toT, fromT);
  if (!fits) go_gemm_kernel<<<RTOT / 64, 256, 0, stream>>>(xb, Wc, bc, mask, gate);
  tri_gemm_kernel<<<dim3(4, 4, 128), 256, 0, stream>>>(toT, fromT, triT);
  out_kernel<<<RTOT / 64, 256, 0, stream>>>(triT, Woutb, ln2w, ln2b, b_out,
                                            (float*)d_out, xb, Wc, bc, mask, fits ? 1 : 0);
}

// Round 9
// 582.362 us; speedup vs baseline: 1.0155x; 1.0155x over previous
//
#include <hip/hip_runtime.h>

#define NSEQ 512
#define DCH 128
#define RTOT (NSEQ * NSEQ) /* 262144 */

typedef __attribute__((ext_vector_type(8))) short bf16x8;
typedef __attribute__((ext_vector_type(4))) float f32x4;

__device__ __forceinline__ unsigned short f2bf(float v) {
  union { float f; unsigned int u; } x; x.f = v;
  unsigned int u = x.u;
  return (unsigned short)((u + 0x7fffu + ((u >> 16) & 1u)) >> 16);
}
__device__ __forceinline__ float bf2f(unsigned short s) {
  union { unsigned int u; float f; } x; x.u = ((unsigned int)s) << 16;
  return x.f;
}
__device__ __forceinline__ float sigmoidf(float x) { return 1.f / (1.f + __expf(-x)); }

// async global->LDS, 16B per lane; LDS dst is wave-uniform base (+ lane*16 implicit)
__device__ __forceinline__ void async16(const unsigned short* g, unsigned short* l) {
  __builtin_amdgcn_global_load_lds(
      (const __attribute__((address_space(1))) unsigned int*)g,
      (__attribute__((address_space(3))) unsigned int*)l, 16, 0, 0);
}

// ---------------------------------------------------------------------------
// prep: pack weights (reordered) into bf16.  Wc rows: [0,128)=to-feat,
// [128,256)=to-gate, [256,384)=from-feat, [384,512)=from-gate, [512,640)=go.
// ---------------------------------------------------------------------------
__global__ void prep_kernel(const float* __restrict__ W_fg, const float* __restrict__ b_fg,
                            const float* __restrict__ W_go, const float* __restrict__ b_go,
                            const float* __restrict__ W_out,
                            unsigned short* __restrict__ Wc, float* __restrict__ bc,
                            unsigned short* __restrict__ Woutb) {
  int idx = blockIdx.x * 256 + threadIdx.x;
  if (idx < 640 * 128) {
    int rr = idx >> 7, k = idx & 127;
    float v, bv;
    if (rr < 512) {
      int m = rr >> 7;
      int srow = (m == 1) ? rr + 128 : (m == 2) ? rr - 128 : rr;
      v = W_fg[srow * 128 + k];
      bv = b_fg[srow];
    } else {
      int srow = rr - 512;
      v = W_go[srow * 128 + k];
      bv = b_go[srow];
    }
    Wc[idx] = f2bf(v);
    if (k == 0) bc[rr] = bv;
  } else {
    int i2 = idx - 640 * 128;
    if (i2 < 128 * 128) Woutb[i2] = f2bf(W_out[i2]);
  }
}

// ---------------------------------------------------------------------------
// K0: LayerNorm over last dim (128) of edges; write x as bf16. 1 wave = 1 row.
// ---------------------------------------------------------------------------
__global__ __launch_bounds__(256) void ln1_kernel(const float* __restrict__ edges,
                                                  const float* __restrict__ w,
                                                  const float* __restrict__ b,
                                                  unsigned short* __restrict__ xb) {
  int wv = threadIdx.x >> 6;
  int lane = threadIdx.x & 63;
  size_t row = (size_t)blockIdx.x * 4 + wv;
  const float2* e = (const float2*)(edges + row * 128);
  float2 v = e[lane];
  float s = v.x + v.y, sq = v.x * v.x + v.y * v.y;
#pragma unroll
  for (int off = 32; off; off >>= 1) {
    s += __shfl_xor(s, off);
    sq += __shfl_xor(sq, off);
  }
  float mu = s * (1.f / 128.f);
  float var = sq * (1.f / 128.f) - mu * mu;
  float rs = rsqrtf(var + 1e-5f);
  int c = lane * 2;
  float x0 = (v.x - mu) * rs * w[c] + b[c];
  float x1 = (v.y - mu) * rs * w[c + 1] + b[c + 1];
  unsigned int packed = (unsigned int)f2bf(x0) | ((unsigned int)f2bf(x1) << 16);
  ((unsigned int*)(xb + row * 128))[lane] = packed;
}

// ---------------------------------------------------------------------------
// K1a: fg GEMM + gating + mask.  Col-split waves; full prologue burst.
// Channel-major stores use runtime plane stride (padded to break the 512KB
// power-of-2 channel aliasing that capped effective BW at ~1.35 TB/s).
// ---------------------------------------------------------------------------
__global__ __launch_bounds__(256) void fg_gemm_kernel(
    const unsigned short* __restrict__ xb, const unsigned short* __restrict__ Wc,
    const float* __restrict__ bc, const int* __restrict__ mask,
    unsigned short* __restrict__ toT, unsigned short* __restrict__ fromT,
    size_t plane) {
  __shared__ unsigned int Cs[128 * 36]; // 128 planes x 64 rows bf16 (pad 36 uints/plane)
  int nb = blockIdx.y;
  int wv = threadIdx.x >> 6, lane = threadIdx.x & 63;
  int qm = lane & 15, quad = lane >> 4;
  int r0 = blockIdx.x * 64;
  int nbase = nb * 256;

  // ---- prologue: every global read issued up front ----
  bf16x8 Areg[4][4]; // [m][kk] — static indexing only (full unroll)
#pragma unroll
  for (int m = 0; m < 4; m++)
#pragma unroll
    for (int kk = 0; kk < 4; kk++)
      Areg[m][kk] = *(const bf16x8*)(xb + (size_t)(r0 + m * 16 + qm) * 128 + kk * 32 + quad * 8);

  bf16x8 Bf[2][4], Bg[2][4];
#pragma unroll
  for (int ft = 0; ft < 2; ft++)
#pragma unroll
    for (int kk = 0; kk < 4; kk++) {
      int ko = kk * 32 + quad * 8;
      Bf[ft][kk] = *(const bf16x8*)(Wc + (size_t)(nbase + wv * 32 + ft * 16 + qm) * 128 + ko);
      Bg[ft][kk] = *(const bf16x8*)(Wc + (size_t)(nbase + 128 + wv * 32 + ft * 16 + qm) * 128 + ko);
    }

  int4 mi4[4];
#pragma unroll
  for (int m = 0; m < 4; m++) mi4[m] = *(const int4*)(mask + r0 + m * 16 + quad * 4);

  float bF_[2], bG_[2];
#pragma unroll
  for (int ft = 0; ft < 2; ft++) {
    int c = wv * 32 + ft * 16 + qm;
    bF_[ft] = bc[nbase + c];
    bG_[ft] = bc[nbase + 128 + c];
  }

#pragma unroll
  for (int m = 0; m < 4; m++) { // 4 row-steps of 16 rows — pure compute
    f32x4 accf[2], accg[2];
#pragma unroll
    for (int ft = 0; ft < 2; ft++) {
      accf[ft] = (f32x4){0.f, 0.f, 0.f, 0.f};
      accg[ft] = (f32x4){0.f, 0.f, 0.f, 0.f};
    }
#pragma unroll
    for (int kk = 0; kk < 4; kk++) {
#pragma unroll
      for (int ft = 0; ft < 2; ft++) {
        accf[ft] = __builtin_amdgcn_mfma_f32_16x16x32_bf16(Areg[m][kk], Bf[ft][kk], accf[ft], 0, 0, 0);
        accg[ft] = __builtin_amdgcn_mfma_f32_16x16x32_bf16(Areg[m][kk], Bg[ft][kk], accg[ft], 0, 0, 0);
      }
    }
    int4 mi = mi4[m];
    float mk[4] = {mi.x ? 1.f : 0.f, mi.y ? 1.f : 0.f, mi.z ? 1.f : 0.f, mi.w ? 1.f : 0.f};
#pragma unroll
    for (int ft = 0; ft < 2; ft++) {
      int c = wv * 32 + ft * 16 + qm; // local col 0..127
      float v0 = (accf[ft][0] + bF_[ft]) * sigmoidf(accg[ft][0] + bG_[ft]) * mk[0];
      float v1 = (accf[ft][1] + bF_[ft]) * sigmoidf(accg[ft][1] + bG_[ft]) * mk[1];
      float v2 = (accf[ft][2] + bF_[ft]) * sigmoidf(accg[ft][2] + bG_[ft]) * mk[2];
      float v3 = (accf[ft][3] + bF_[ft]) * sigmoidf(accg[ft][3] + bG_[ft]) * mk[3];
      unsigned int u0 = (unsigned int)f2bf(v0) | ((unsigned int)f2bf(v1) << 16);
      unsigned int u1 = (unsigned int)f2bf(v2) | ((unsigned int)f2bf(v3) << 16);
      *(uint2*)(Cs + c * 36 + m * 8 + quad * 2) = (uint2){u0, u1};
    }
  }
  __syncthreads();
  { // wave writes its own 32 planes; 8 lanes/plane -> 128B contiguous lines
    unsigned short* dst = (nb == 0) ? toT : fromT;
    int pl = lane >> 3, lo = lane & 7;
#pragma unroll
    for (int i = 0; i < 4; i++) {
      int p = wv * 32 + i * 8 + pl;
      uint4 v = *(const uint4*)(Cs + p * 36 + lo * 4);
      *(uint4*)(dst + (size_t)p * plane + r0 + lo * 8) = v;
    }
  }
}

// ---------------------------------------------------------------------------
// K1b (FALLBACK ONLY, used when workspace too small to de-alias triT):
// out_gate = sigmoid(x @ W_go^T + b_go) * mask, fp32, into d_out.
// ---------------------------------------------------------------------------
__global__ __launch_bounds__(256) void go_gemm_kernel(
    const unsigned short* __restrict__ xb, const unsigned short* __restrict__ Wc,
    const float* __restrict__ bc, const int* __restrict__ mask,
    float* __restrict__ gate_out) {
  int wv = threadIdx.x >> 6, lane = threadIdx.x & 63;
  int qm = lane & 15, quad = lane >> 4;
  int rw = blockIdx.x * 64 + wv * 16;

  f32x4 acc[8];
#pragma unroll
  for (int t = 0; t < 8; t++) acc[t] = (f32x4){0.f, 0.f, 0.f, 0.f};

#pragma unroll
  for (int kk = 0; kk < 4; kk++) {
    int ko = kk * 32 + quad * 8;
    bf16x8 a = *(const bf16x8*)(xb + (size_t)(rw + qm) * 128 + ko);
#pragma unroll
    for (int t = 0; t < 8; t++) {
      bf16x8 bf = *(const bf16x8*)(Wc + (size_t)(512 + t * 16 + qm) * 128 + ko);
      acc[t] = __builtin_amdgcn_mfma_f32_16x16x32_bf16(a, bf, acc[t], 0, 0, 0);
    }
  }

  int rbase = rw + quad * 4;
  int4 mi = *(const int4*)(mask + rbase);
  float mk[4] = {mi.x ? 1.f : 0.f, mi.y ? 1.f : 0.f, mi.z ? 1.f : 0.f, mi.w ? 1.f : 0.f};
#pragma unroll
  for (int t = 0; t < 8; t++) {
    int c = t * 16 + qm;
    float bG = bc[512 + c];
#pragma unroll
    for (int reg = 0; reg < 4; reg++) {
      float g = sigmoidf(acc[t][reg] + bG) * mk[reg];
      gate_out[(size_t)(rbase + reg) * 128 + c] = g;
    }
  }
}

// ---------------------------------------------------------------------------
// K2: tri[d] = To_d (512x512) @ From_d^T, 128 batched NT GEMMs.
// 128x128 tile/block, BK=64, global_load_lds(16B) staging, 4 waves x (4x4)
// MFMA accs.  XCD d-clustered swizzle (bijective).  Plane stride padded.
// ---------------------------------------------------------------------------
__global__ __launch_bounds__(256) void tri_gemm_kernel(
    const unsigned short* __restrict__ toT, const unsigned short* __restrict__ fromT,
    unsigned short* __restrict__ triT, size_t plane) {
  __shared__ unsigned short smem[128 * 136]; // K-loop: As=[0,8192) Bs=[8192,16384); epilogue: C 128x136
  unsigned short* As = smem;
  unsigned short* Bs = smem + 128 * 64;

  // bijective remap of (x,y,z) -> (i0,j0,d), d-clustered per XCD
  int n = (int)(blockIdx.x + (blockIdx.y << 2) + (blockIdx.z << 4)); // 0..2047
  int xcd = n & 7, s = n >> 3;                                        // s: 0..255
  int d = xcd * 16 + (s >> 4);
  int xy = s & 15;
  int i0 = (xy & 3) * 128, j0 = (xy >> 2) * 128;

  int tid = threadIdx.x, w = tid >> 6, lane = tid & 63;
  int qm = lane & 15, quad = lane >> 4;
  int wm = w >> 1, wn = w & 1;
  const unsigned short* A = toT + (size_t)d * plane;
  const unsigned short* B = fromT + (size_t)d * plane;
  int lr = lane >> 3, lk = (lane & 7) * 8;

  f32x4 acc[4][4];
#pragma unroll
  for (int m = 0; m < 4; m++)
#pragma unroll
    for (int n2 = 0; n2 < 4; n2++) acc[m][n2] = (f32x4){0.f, 0.f, 0.f, 0.f};

  for (int kb = 0; kb < 512; kb += 64) {
    __syncthreads(); // prev compute done reading LDS
#pragma unroll
    for (int q = 0; q < 4; q++) {
      int blk = w * 4 + q; // 16 row-blocks of 8 rows each
      async16(A + (size_t)(i0 + blk * 8 + lr) * 512 + kb + lk, As + blk * 512);
      async16(B + (size_t)(j0 + blk * 8 + lr) * 512 + kb + lk, Bs + blk * 512);
    }
    __syncthreads(); // loads drained (compiler emits vmcnt(0) before barrier)
#pragma unroll
    for (int kk = 0; kk < 2; kk++) {
      bf16x8 af[4], bfr[4];
#pragma unroll
      for (int m = 0; m < 4; m++)
        af[m] = *(const bf16x8*)(As + (wm * 64 + m * 16 + qm) * 64 + kk * 32 + quad * 8);
#pragma unroll
      for (int n2 = 0; n2 < 4; n2++)
        bfr[n2] = *(const bf16x8*)(Bs + (wn * 64 + n2 * 16 + qm) * 64 + kk * 32 + quad * 8);
#pragma unroll
      for (int m = 0; m < 4; m++)
#pragma unroll
        for (int n2 = 0; n2 < 4; n2++)
          acc[m][n2] = __builtin_amdgcn_mfma_f32_16x16x32_bf16(af[m], bfr[n2], acc[m][n2], 0, 0, 0);
    }
  }

  __syncthreads(); // done with As/Bs; reuse smem as C 128x136 (pad keeps 16B align, kills conflicts)
#pragma unroll
  for (int m = 0; m < 4; m++) {
    int rb = wm * 64 + m * 16 + quad * 4;
#pragma unroll
    for (int n2 = 0; n2 < 4; n2++) {
      int col = wn * 64 + n2 * 16 + qm;
#pragma unroll
      for (int reg = 0; reg < 4; reg++)
        smem[(rb + reg) * 136 + col] = f2bf(acc[m][n2][reg]);
    }
  }
  __syncthreads();
  { // each (row, half) copies its FULL 64-short half: 8 x uint4
    int row = tid >> 1, half = tid & 1;
    const uint4* src = (const uint4*)(smem + row * 136 + half * 64);
    uint4 v[8];
#pragma unroll
    for (int u = 0; u < 8; u++) v[u] = src[u];
    uint4* dst = (uint4*)(triT + (size_t)d * plane + (size_t)(i0 + row) * 512 + j0 + half * 64);
#pragma unroll
    for (int u = 0; u < 8; u++) dst[u] = v[u];
  }
}

// ---------------------------------------------------------------------------
// K3: LN2 over d=128 of tri (channel-major input), @ W_out^T + b_out, * gate.
// Round-5 structure (64-row blocks, prologue burst, a2 pipeline); staging
// reads use padded plane stride.
// ---------------------------------------------------------------------------
__global__ __launch_bounds__(256) void out_kernel(
    const unsigned short* __restrict__ triT, const unsigned short* __restrict__ Woutb,
    const float* __restrict__ ln2w, const float* __restrict__ ln2b,
    const float* __restrict__ b_out, float* __restrict__ out,
    const unsigned short* __restrict__ xb, const unsigned short* __restrict__ Wc,
    const float* __restrict__ bc, const int* __restrict__ mask, int fuse,
    size_t plane) {
  __shared__ unsigned short nt[64][136];
  __shared__ float mu_s[64], rs_s[64];
  int r0 = blockIdx.x * 64;
  int tid = threadIdx.x;
  int wv = tid >> 6, lane = tid & 63;
  int qm = lane & 15, quad = lane >> 4;

  // ---- prologue: issue every global read up front (max MLP) ----
  int dch = tid >> 1, half = tid & 1;
  const uint4* src = (const uint4*)(triT + (size_t)dch * plane + r0 + half * 32);
  uint4 sv0 = src[0], sv1 = src[1], sv2 = src[2], sv3 = src[3];

  // B fragments for this wave's 32 output cols.
  bf16x8 Bo[2][4], Bg[2][4];
#pragma unroll
  for (int ft = 0; ft < 2; ft++)
#pragma unroll
    for (int kk = 0; kk < 4; kk++) {
      int c = wv * 32 + ft * 16 + qm;
      int ko = kk * 32 + quad * 8;
      Bo[ft][kk] = *(const bf16x8*)(Woutb + (size_t)c * 128 + ko);
      if (fuse) Bg[ft][kk] = *(const bf16x8*)(Wc + (size_t)(512 + c) * 128 + ko);
    }

  // masks for all 4 m-steps; bias scalars.
  int4 mi4[4];
  float bo_[2], bG_[2];
#pragma unroll
  for (int ft = 0; ft < 2; ft++) {
    int c = wv * 32 + ft * 16 + qm;
    bo_[ft] = b_out[c];
    bG_[ft] = fuse ? bc[512 + c] : 0.f;
  }
  if (fuse) {
#pragma unroll
    for (int m = 0; m < 4; m++) mi4[m] = *(const int4*)(mask + r0 + m * 16 + quad * 4);
  }

  // gate A2: prefetch m=0 (double-buffered across the m-loop).
  const unsigned short* xA = xb + (size_t)(r0 + qm) * 128 + quad * 8;
  bf16x8 a2cur[4], a2nxt[4];
  if (fuse) {
#pragma unroll
    for (int kk = 0; kk < 4; kk++) a2cur[kk] = *(const bf16x8*)(xA + kk * 32);
  }

  { // LDS staging writes (vmcnt waits only on the sv0..3 loads)
    uint4 v[4] = {sv0, sv1, sv2, sv3};
    const unsigned short* pv = (const unsigned short*)v;
#pragma unroll
    for (int u = 0; u < 32; u++) nt[half * 32 + u][dch] = pv[u];
  }
  __syncthreads();

  { // LN2 stats: 4 lanes per position
    int p = tid >> 2, part = tid & 3;
    float s = 0.f, sq = 0.f;
#pragma unroll
    for (int u = 0; u < 4; u++) {
      bf16x8 v = *(const bf16x8*)(&nt[p][part * 32 + u * 8]);
#pragma unroll
      for (int e = 0; e < 8; e++) {
        float f = bf2f((unsigned short)v[e]);
        s += f; sq += f * f;
      }
    }
    s += __shfl_xor(s, 1); sq += __shfl_xor(sq, 1);
    s += __shfl_xor(s, 2); sq += __shfl_xor(sq, 2);
    float mu = s * (1.f / 128.f);
    float var = sq * (1.f / 128.f) - mu * mu;
    if (part == 0) { mu_s[p] = mu; rs_s[p] = rsqrtf(var + 1e-5f); }
  }
  __syncthreads();

#pragma unroll
  for (int m = 0; m < 4; m++) { // 4 row-steps of 16 rows
    // prefetch next m's gate A2 first: latency hides under afr VALU + MFMA
    if (fuse && m < 3) {
#pragma unroll
      for (int kk = 0; kk < 4; kk++)
        a2nxt[kk] = *(const bf16x8*)(xA + (m + 1) * 2048 + kk * 32);
    }

    int rl = m * 16 + qm;
    float mu = mu_s[rl], rs = rs_s[rl];

    // Build normalized A-fragments in registers.
    bf16x8 afr[4];
#pragma unroll
    for (int kk = 0; kk < 4; kk++) {
      int ko = kk * 32 + quad * 8;
      bf16x8 raw = *(const bf16x8*)(&nt[rl][ko]);
#pragma unroll
      for (int e = 0; e < 8; e++) {
        float wf = ln2w[ko + e], bv = ln2b[ko + e];
        afr[kk][e] = (short)f2bf((bf2f((unsigned short)raw[e]) - mu) * rs * wf + bv);
      }
    }

    f32x4 accO[2], accG[2];
#pragma unroll
    for (int ft = 0; ft < 2; ft++) {
      accO[ft] = (f32x4){0.f, 0.f, 0.f, 0.f};
      accG[ft] = (f32x4){0.f, 0.f, 0.f, 0.f};
    }
#pragma unroll
    for (int kk = 0; kk < 4; kk++) {
#pragma unroll
      for (int ft = 0; ft < 2; ft++)
        accO[ft] = __builtin_amdgcn_mfma_f32_16x16x32_bf16(afr[kk], Bo[ft][kk], accO[ft], 0, 0, 0);
      if (fuse) {
#pragma unroll
        for (int ft = 0; ft < 2; ft++)
          accG[ft] = __builtin_amdgcn_mfma_f32_16x16x32_bf16(a2cur[kk], Bg[ft][kk], accG[ft], 0, 0, 0);
      }
    }

    int rbase = r0 + m * 16 + quad * 4;
    if (fuse) {
      int4 mi = mi4[m];
      float mk[4] = {mi.x ? 1.f : 0.f, mi.y ? 1.f : 0.f, mi.z ? 1.f : 0.f, mi.w ? 1.f : 0.f};
#pragma unroll
      for (int ft = 0; ft < 2; ft++) {
        int c = wv * 32 + ft * 16 + qm;
#pragma unroll
        for (int reg = 0; reg < 4; reg++) {
          float g = sigmoidf(accG[ft][reg] + bG_[ft]) * mk[reg];
          out[(size_t)(rbase + reg) * 128 + c] = (accO[ft][reg] + bo_[ft]) * g;
        }
      }
      // rotate double-buffer (register moves, static after unroll)
#pragma unroll
      for (int kk = 0; kk < 4; kk++) a2cur[kk] = a2nxt[kk];
    } else {
#pragma unroll
      for (int ft = 0; ft < 2; ft++) {
        int c = wv * 32 + ft * 16 + qm;
#pragma unroll
        for (int reg = 0; reg < 4; reg++) {
          size_t off = (size_t)(rbase + reg) * 128 + c;
          out[off] = (accO[ft][reg] + bo_[ft]) * out[off]; // out[] holds gate
        }
      }
    }
  }
}

// ---------------------------------------------------------------------------
extern "C" void kernel_launch(void* const* d_in, const int* in_sizes, int n_in,
                              void* d_out, int out_size, void* d_ws, size_t ws_size,
                              hipStream_t stream) {
  const float* edges = (const float*)d_in[0];
  const int* mask = (const int*)d_in[1];
  const float* ln1w = (const float*)d_in[2];
  const float* ln1b = (const float*)d_in[3];
  const float* W_fg = (const float*)d_in[4];
  const float* b_fg = (const float*)d_in[5];
  const float* W_go = (const float*)d_in[6];
  const float* b_go = (const float*)d_in[7];
  const float* ln2w = (const float*)d_in[8];
  const float* ln2b = (const float*)d_in[9];
  const float* W_out = (const float*)d_in[10];
  const float* b_out = (const float*)d_in[11];

  char* ws = (char*)d_ws;
  const size_t SZ = (size_t)RTOT * DCH * 2;       // 64 MiB (xb, row-major)
  const size_t PLANEP = (size_t)RTOT + 1024;      // +2KB/plane: break 512KB channel aliasing
  const size_t SZP = PLANEP * DCH * 2;            // ~64.25 MiB per padded channel-major buffer
  const size_t WSMALL = 0x40000;                  // 256 KiB: Wc+bc+Woutb, padded

  unsigned short* xb = (unsigned short*)ws;
  float* gate = (float*)d_out;

  bool fits = ws_size >= SZ + 3 * SZP + WSMALL;
  size_t plane;
  unsigned short *toT, *fromT, *triT, *Wc, *Woutb;
  float* bc;
  if (fits) {
    plane = PLANEP;
    toT = (unsigned short*)(ws + SZ);
    fromT = (unsigned short*)(ws + SZ + SZP);
    triT = (unsigned short*)(ws + SZ + 2 * SZP);
    Wc = (unsigned short*)(ws + SZ + 3 * SZP);
    bc = (float*)(ws + SZ + 3 * SZP + 640 * 128 * 2);
    Woutb = (unsigned short*)(ws + SZ + 3 * SZP + 640 * 128 * 2 + 640 * 4);
  } else {
    plane = RTOT; // legacy unpadded layout; triT aliases xb; gate via go_gemm
    toT = (unsigned short*)(ws + SZ);
    fromT = (unsigned short*)(ws + 2 * SZ);
    Wc = (unsigned short*)(ws + 3 * SZ);
    bc = (float*)(ws + 3 * SZ + 640 * 128 * 2);
    Woutb = (unsigned short*)(ws + 3 * SZ + 640 * 128 * 2 + 640 * 4);
    triT = xb;
  }

  prep_kernel<<<384, 256, 0, stream>>>(W_fg, b_fg, W_go, b_go, W_out, Wc, bc, Woutb);
  ln1_kernel<<<RTOT / 4, 256, 0, stream>>>(edges, ln1w, ln1b, xb);
  fg_gemm_kernel<<<dim3(RTOT / 64, 2), 256, 0, stream>>>(xb, Wc, bc, mask, toT, fromT, plane);
  if (!fits) go_gemm_kernel<<<RTOT / 64, 256, 0, stream>>>(xb, Wc, bc, mask, gate);
  tri_gemm_kernel<<<dim3(4, 4, 128), 256, 0, stream>>>(toT, fromT, triT, plane);
  out_kernel<<<RTOT / 64, 256, 0, stream>>>(triT, Woutb, ln2w, ln2b, b_out,
                                            (float*)d_out, xb, Wc, bc, mask, fits ? 1 : 0, plane);
}